// Round 1
// baseline (491.749 us; speedup 1.0000x reference)
//
#include <hip/hip_runtime.h>

// RANGE2BEV: scatter range-view features (B,C,RH,RW) into BEV grid (B,C,D,W,H)
// with last-write-wins duplicate resolution (np fancy-assignment semantics).
//
// Strategy:
//   pass 1: init winner[b][cell] = -1          (cell = (zbin*W+xf)*H+yf)
//   pass 2: per point, atomicMax(winner, i)    (largest point index wins)
//   pass 3: per output element (coalesced float4), gather feat[b][c][winner]
//           or 0 — writes all 360 MB exactly once, coalesced.

namespace {

constexpr int Wg    = 400;          // (40-(-40))/0.2
constexpr int Hg    = 352;          // (70.4-0)/0.2
constexpr int Dg    = 5;            // (1-(-3))/0.8
constexpr int NCELL = Dg * Wg * Hg; // 704000
constexpr int NPTS  = 64 * 2048;    // 131072 points per batch
constexpr int CC    = 64;
constexpr int BB    = 2;

__global__ void init_winner_k(int* __restrict__ winner) {
    int idx = blockIdx.x * blockDim.x + threadIdx.x;
    if (idx < BB * NCELL) winner[idx] = -1;
}

__global__ void scatter_winner_k(const float* __restrict__ xyz,
                                 int* __restrict__ winner) {
    int idx = blockIdx.x * blockDim.x + threadIdx.x;
    if (idx >= BB * NPTS) return;
    int b = idx / NPTS;
    int i = idx - b * NPTS;
    const float* base = xyz + (size_t)b * 3 * NPTS;
    float xp = base[i];
    float yp = base[NPTS + i];
    float zp = base[2 * NPTS + i];
    // valid z range [-3, 1)
    if (!(zp >= -3.0f && zp < 1.0f)) return;
    int zbin  = (int)floorf((zp + 3.0f) / 0.8f);        // in [0,4]
    int x_img = (int)(-yp / 0.2f) + 200;                // trunc-toward-zero, f32 div
    int y_img = (int)(-xp / 0.2f) + 352;
    x_img = min(max(x_img, 0), Wg - 1);
    y_img = min(max(y_img, 0), Hg - 1);
    int xf = (Wg - 1) - x_img;
    int yf = (Hg - 1) - y_img;
    int cell = (zbin * Wg + xf) * Hg + yf;
    atomicMax(winner + b * NCELL + cell, i);            // last (largest i) wins
}

__global__ void write_out_k(const float* __restrict__ feat,
                            const int* __restrict__ winner,
                            float* __restrict__ out) {
    int idx = blockIdx.x * blockDim.x + threadIdx.x;
    if (idx >= BB * CC * NCELL / 4) return;
    int e    = idx * 4;                 // NCELL % 4 == 0, group stays in one (b,c) row
    int bc   = e / NCELL;               // b*CC + c  (const divide -> magic mul)
    int cell = e - bc * NCELL;
    int b    = bc >> 6;
    const int4 w4 = *reinterpret_cast<const int4*>(winner + b * NCELL + cell);
    const float* frow = feat + (size_t)bc * NPTS;       // range_res[b][c][:]
    float4 v;
    v.x = (w4.x >= 0) ? frow[w4.x] : 0.0f;
    v.y = (w4.y >= 0) ? frow[w4.y] : 0.0f;
    v.z = (w4.z >= 0) ? frow[w4.z] : 0.0f;
    v.w = (w4.w >= 0) ? frow[w4.w] : 0.0f;
    *reinterpret_cast<float4*>(out + e) = v;            // coalesced 16B store
}

} // namespace

extern "C" void kernel_launch(void* const* d_in, const int* in_sizes, int n_in,
                              void* d_out, int out_size, void* d_ws, size_t ws_size,
                              hipStream_t stream) {
    const float* range_res = (const float*)d_in[0];   // (B,C,RH,RW) f32
    const float* xyz       = (const float*)d_in[1];   // (B,3,RH,RW) f32
    float* out             = (float*)d_out;           // (B,C,D,W,H) f32
    int* winner            = (int*)d_ws;              // BB*NCELL ints = 5.6 MB

    {
        int total = BB * NCELL;
        init_winner_k<<<(total + 255) / 256, 256, 0, stream>>>(winner);
    }
    {
        int total = BB * NPTS;
        scatter_winner_k<<<(total + 255) / 256, 256, 0, stream>>>(xyz, winner);
    }
    {
        int total = BB * CC * NCELL / 4;
        write_out_k<<<(total + 255) / 256, 256, 0, stream>>>(range_res, winner, out);
    }
}